// Round 6
// baseline (91.309 us; speedup 1.0000x reference)
//
#include <hip/hip_runtime.h>
#include <hip/hip_bf16.h>

typedef unsigned short u16;
typedef unsigned int   u32;
typedef __attribute__((ext_vector_type(8))) short bf16x8;
typedef __attribute__((ext_vector_type(4))) float f32x4;

#define NB    16
#define CIN   256
#define TDIM  256
#define VDIM  64
#define PCOL  192          // output columns = C_OUT*NEW_NODES, p = co*64 + j
#define NCHX  256          // x-part K chunks (64 wide each)
#define NCH   259          // + 3 seed chunks ; K = 16576
#define MTOT  4096         // N*T
#define CHUNK_U16 12288    // PCOL*64 bf16 per chunk
#define WT_BYTES ((size_t)NCH * CHUNK_U16 * 2)   // 6,365,184 B

// ---- helpers ---------------------------------------------------------------
__device__ __forceinline__ u16 f2bf(float f) {            // f32 -> bf16 RNE
  u32 u = __builtin_bit_cast(u32, f);
  u32 r = u + 0x7fffu + ((u >> 16) & 1u);
  return (u16)(r >> 16);
}
__device__ __forceinline__ u32 pk2(float a, float b) {
  return (u32)f2bf(a) | ((u32)f2bf(b) << 16);
}

// ---- kernel 1: W f32 -> bf16 granule image (UNswizzled: B is reg-loaded) ---
// granule (16B) g = p*8 + q holds W[p][k = ch*64 + q*8 .. +8] as bf16x8
__global__ void prep_w(const float* __restrict__ W, u16* __restrict__ Wt) {
  int u  = blockIdx.x * 256 + threadIdx.x;   // exactly NCH*PCOL*8 units
  int q  = u & 7;
  int p  = (u >> 3) % PCOL;
  int ch = u / (PCOL * 8);
  int j = p & 63, co = p >> 6;
  const float* src = W + (size_t)(j * 3 + co) * 16576 + ch * 64 + q * 8;
  float4 fa = *(const float4*)src;
  float4 fb = *(const float4*)(src + 4);
  uint4 v;
  v.x = pk2(fa.x, fa.y); v.y = pk2(fa.z, fa.w);
  v.z = pk2(fb.x, fb.y); v.w = pk2(fb.z, fb.w);
  ((uint4*)Wt)[(size_t)ch * 1536 + p * 8 + q] = v;
}

// ---- kernel 2: bf16 MFMA GEMM. A: LDS double-buffer, depth-2 reg prefetch
// (T14). B: pure register path — each lane global-loads its own 6 MFMA
// fragments (16B granules) with a full iteration of latency slack. Barrier
// only guards A's LDS (lgkmcnt(0)); NO vmcnt drain anywhere in the loop.
__global__ __launch_bounds__(256, 2)
void gemm_bf16(const float* __restrict__ x, const float* __restrict__ seeds,
               const u16* __restrict__ Wt, float* __restrict__ dst,
               const float* __restrict__ bias, int S) {
  __shared__ __align__(16) u16 ldsA[2][4096];   // per buf: 64x64 bf16 A tile
  const int tid  = threadIdx.x;
  const int lane = tid & 63;
  const int wid  = tid >> 6;
  const int bid  = blockIdx.x;
  int mblk, ksp;
  if (S == 8) { ksp = bid & 7;  mblk = bid >> 3; }   // XCD-pinned split
  else        { mblk = bid & 63; ksp = bid >> 6; }
  const int n  = mblk >> 2;
  const int t0 = (mblk & 3) << 6;
  const int c0 = (NCH * ksp) / S;
  const int c1 = (NCH * (ksp + 1)) / S;

  const int q0 = tid & 7;          // A staging: 8-float unit within row
  const int m0 = tid >> 3;         // A staging: rows m0, m0+32
  const int lr = lane & 15, lq = lane >> 4;

  f32x4 acc[4][3] = {};

  struct ASet { float4 r0a, r0b, r1a, r1b; };
  struct BSet { uint4 k0n0, k0n1, k0n2, k1n0, k1n1, k1n2; };
  ASet AX, AY;
  BSet BX, BY;

  // per-lane B granule base: (p = wid*48 + lr, q = lq); constant offsets cover
  // nt (+16p = +2048B) and ks (+4q = +64B)
  const char* bgran = (const char*)Wt + ((wid * 48 + lr) * 8 + lq) * 16;

  auto Ai = [&](int ch, ASet& s) {   // 4 x global_load_dwordx4 into VGPRs
    const float *a0, *a1;
    if (ch < NCHX) {
      a0 = x + (((size_t)n * CIN + ch) * TDIM + (t0 + m0)) * VDIM + q0 * 8;
      a1 = a0 + (size_t)32 * VDIM;
    } else {
      a0 = seeds + ((size_t)n * TDIM + (t0 + m0)) * 192 + (ch - NCHX) * 64 + q0 * 8;
      a1 = a0 + (size_t)32 * 192;
    }
    s.r0a = *(const float4*)a0; s.r0b = *(const float4*)(a0 + 4);
    s.r1a = *(const float4*)a1; s.r1b = *(const float4*)(a1 + 4);
  };
  auto Bi = [&](int ch, BSet& s) {   // 6 x global_load_dwordx4 (L2-resident Wt)
    const uint4* g = (const uint4*)(bgran + (size_t)ch * 24576);
    s.k0n0 = g[0];   s.k1n0 = g[4];          // +0, +64B
    s.k0n1 = g[128]; s.k1n1 = g[132];        // +2048B, +2112B
    s.k0n2 = g[256]; s.k1n2 = g[260];        // +4096B, +4160B
  };
  auto CONV = [&](const ASet& s, int buf) {  // bf16-pack + swizzled ds_write
    uint4 v;
    v.x = pk2(s.r0a.x, s.r0a.y); v.y = pk2(s.r0a.z, s.r0a.w);
    v.z = pk2(s.r0b.x, s.r0b.y); v.w = pk2(s.r0b.z, s.r0b.w);
    ((uint4*)&ldsA[buf][0])[m0 * 8 + (q0 ^ (m0 & 7))] = v;
    int m1 = m0 + 32;
    v.x = pk2(s.r1a.x, s.r1a.y); v.y = pk2(s.r1a.z, s.r1a.w);
    v.z = pk2(s.r1b.x, s.r1b.y); v.w = pk2(s.r1b.z, s.r1b.w);
    ((uint4*)&ldsA[buf][0])[m1 * 8 + (q0 ^ (m1 & 7))] = v;
  };

  auto COMPUTE = [&](int buf, const BSet& B) {
    const u16* L = &ldsA[buf][0];
    #pragma unroll
    for (int ks = 0; ks < 2; ++ks) {
      const int q = ks * 4 + lq;
      bf16x8 af[4];
      #pragma unroll
      for (int mt = 0; mt < 4; ++mt) {
        int m = mt * 16 + lr;
        af[mt] = *(const bf16x8*)(L + (m * 8 + (q ^ (m & 7))) * 8);
      }
      bf16x8 b0 = __builtin_bit_cast(bf16x8, ks ? B.k1n0 : B.k0n0);
      bf16x8 b1 = __builtin_bit_cast(bf16x8, ks ? B.k1n1 : B.k0n1);
      bf16x8 b2 = __builtin_bit_cast(bf16x8, ks ? B.k1n2 : B.k0n2);
      #pragma unroll
      for (int mt = 0; mt < 4; ++mt) {
        acc[mt][0] = __builtin_amdgcn_mfma_f32_16x16x32_bf16(af[mt], b0, acc[mt][0], 0, 0, 0);
        acc[mt][1] = __builtin_amdgcn_mfma_f32_16x16x32_bf16(af[mt], b1, acc[mt][1], 0, 0, 0);
        acc[mt][2] = __builtin_amdgcn_mfma_f32_16x16x32_bf16(af[mt], b2, acc[mt][2], 0, 0, 0);
      }
    }
  };

  // ---- prologue: B(c0),B(c0+1) -> regs; A(c0),A(c0+1) -> regs; CONV A(c0) --
  Bi(c0, BX);
  if (c0 + 1 < c1) Bi(c0 + 1, BY);
  Ai(c0, AX);
  if (c0 + 1 < c1) Ai(c0 + 1, AY);
  __builtin_amdgcn_sched_barrier(0);
  CONV(AX, 0);                       // compiler auto-waits A(c0) loads
  asm volatile("s_waitcnt lgkmcnt(0)" ::: "memory");
  __builtin_amdgcn_sched_barrier(0);
  __builtin_amdgcn_s_barrier();
  __builtin_amdgcn_sched_barrier(0);

  // ---- main loop, unrolled x2 (named reg-sets; rule #20) -------------------
#define PHASE(BUF, AP, AN, BC)                                                \
  {                                                                           \
    const bool hasN  = (ch + 1 < c1);                                         \
    const bool hasNN = (ch + 2 < c1);                                         \
    if (hasNN) Ai(ch + 2, AN);                                                \
    __builtin_amdgcn_sched_barrier(0);                                        \
    COMPUTE(BUF, BC);                                                         \
    __builtin_amdgcn_sched_barrier(0);                                        \
    if (hasNN) Bi(ch + 2, BC);     /* reload just-consumed set */             \
    if (!hasN) break;                                                         \
    CONV(AP, (BUF) ^ 1);                                                      \
    asm volatile("s_waitcnt lgkmcnt(0)" ::: "memory");                        \
    __builtin_amdgcn_sched_barrier(0);                                        \
    __builtin_amdgcn_s_barrier();                                             \
    __builtin_amdgcn_sched_barrier(0);                                        \
  }

  int ch = c0;
  while (true) {
    PHASE(0, AY, AX, BX)     // compute ch (even slot)
    ++ch;
    PHASE(1, AX, AY, BY)     // compute ch (odd slot)
    ++ch;
  }
#undef PHASE

  // epilogue: C layout col=lane&15, row=(lane>>4)*4+reg  [measured m89/m91]
  float* dbase = dst + (size_t)ksp * MTOT * PCOL;
  #pragma unroll
  for (int mt = 0; mt < 4; ++mt)
    #pragma unroll
    for (int nt = 0; nt < 3; ++nt) {
      int col = wid * 48 + nt * 16 + lr;
      float bv = bias ? bias[(col & 63) * 3 + (col >> 6)] : 0.f;
      #pragma unroll
      for (int r = 0; r < 4; ++r) {
        int row = mblk * 64 + mt * 16 + lq * 4 + r;
        dbase[(size_t)row * PCOL + col] = acc[mt][nt][r] + bv;
      }
    }
}

// ---- kernel 3: deterministic K-split reduction + bias ----------------------
__global__ void reduce_k(const float* __restrict__ part, const float* __restrict__ b,
                         float* __restrict__ out, int S) {
  int i4 = (blockIdx.x * 256 + threadIdx.x) * 4;   // exact: MTOT*PCOL/4 threads
  float4 a = *(const float4*)&part[i4];
  for (int s = 1; s < S; ++s) {
    const float4 v = *(const float4*)&part[(size_t)s * (MTOT * PCOL) + i4];
    a.x += v.x; a.y += v.y; a.z += v.z; a.w += v.w;
  }
  int p0 = i4 % PCOL;
  a.x += b[((p0 + 0) & 63) * 3 + ((p0 + 0) >> 6)];
  a.y += b[((p0 + 1) & 63) * 3 + ((p0 + 1) >> 6)];
  a.z += b[((p0 + 2) & 63) * 3 + ((p0 + 2) >> 6)];
  a.w += b[((p0 + 3) & 63) * 3 + ((p0 + 3) >> 6)];
  *(float4*)&out[i4] = a;
}

// ---- insurance fallback if ws too small for the Wt image (unlikely) --------
__global__ void fallback_k(const float* __restrict__ x, const float* __restrict__ seeds,
                           const float* __restrict__ W, const float* __restrict__ b,
                           float* __restrict__ out) {
  __shared__ float mk[512];
  int m = blockIdx.x, n = m >> 8, t = m & 255, p = threadIdx.x;
  float acc = 0.f;
  for (int k0 = 0; k0 < 16576; k0 += 512) {
    int kn = min(512, 16576 - k0);
    __syncthreads();
    for (int i = threadIdx.x; i < kn; i += 256) {
      int k = k0 + i;
      mk[i] = (k < 16384)
                ? x[(((size_t)n * 256 + (k >> 6)) * 256 + t) * 64 + (k & 63)]
                : seeds[((size_t)n * 256 + t) * 192 + (k - 16384)];
    }
    __syncthreads();
    if (p < PCOL) {
      const float* wr = W + (size_t)((p & 63) * 3 + (p >> 6)) * 16576 + k0;
      for (int i = 0; i < kn; ++i) acc += mk[i] * wr[i];
    }
  }
  if (p < PCOL) out[(size_t)m * PCOL + p] = acc + b[(p & 63) * 3 + (p >> 6)];
}

extern "C" void kernel_launch(void* const* d_in, const int* in_sizes, int n_in,
                              void* d_out, int out_size, void* d_ws, size_t ws_size,
                              hipStream_t stream) {
  (void)in_sizes; (void)n_in; (void)out_size;
  const float* x     = (const float*)d_in[0];
  const float* seeds = (const float*)d_in[1];
  const float* W     = (const float*)d_in[2];
  const float* b     = (const float*)d_in[3];
  float* out = (float*)d_out;

  if (ws_size < WT_BYTES) {              // no room for bf16 weight image
    fallback_k<<<dim3(MTOT), dim3(256), 0, stream>>>(x, seeds, W, b, out);
    return;
  }
  u16* Wt = (u16*)d_ws;
  int S = 8;                             // K-split for grid = 64*S blocks
  while (S > 1 && WT_BYTES + (size_t)S * MTOT * PCOL * 4 > ws_size) S >>= 1;
  if (WT_BYTES + (size_t)S * MTOT * PCOL * 4 > ws_size) S = 1;

  prep_w<<<dim3((NCH * PCOL * 8) / 256), dim3(256), 0, stream>>>(W, Wt);
  if (S == 1) {
    gemm_bf16<<<dim3(64), dim3(256), 0, stream>>>(x, seeds, Wt, out, b, 1);
  } else {
    float* part = (float*)((char*)d_ws + WT_BYTES);
    gemm_bf16<<<dim3(64 * S), dim3(256), 0, stream>>>(x, seeds, Wt, part, nullptr, S);
    reduce_k<<<dim3(MTOT * PCOL / 4 / 256), dim3(256), 0, stream>>>(part, b, out, S);
  }
}

// Round 7
// 80.941 us; speedup vs baseline: 1.1281x; 1.1281x over previous
//
#include <hip/hip_runtime.h>
#include <hip/hip_bf16.h>

typedef unsigned short u16;
typedef unsigned int   u32;
typedef __attribute__((ext_vector_type(8))) short bf16x8;
typedef __attribute__((ext_vector_type(4))) float f32x4;

#define NB    16
#define CIN   256
#define TDIM  256
#define VDIM  64
#define PCOL  192          // output columns = C_OUT*NEW_NODES, p = co*64 + j
#define NCHX  256          // x-part K chunks (64 wide each)
#define NCH   259          // + 3 seed chunks ; K = 16576
#define MTOT  4096         // N*T
#define CHUNK_U16 12288    // PCOL*64 bf16 per chunk
#define WT_BYTES ((size_t)NCH * CHUNK_U16 * 2)   // 6,365,184 B

// ---- helpers ---------------------------------------------------------------
__device__ __forceinline__ u16 f2bf(float f) {            // f32 -> bf16 RNE
  u32 u = __builtin_bit_cast(u32, f);
  u32 r = u + 0x7fffu + ((u >> 16) & 1u);
  return (u16)(r >> 16);
}
__device__ __forceinline__ u32 pk2(float a, float b) {
  return (u32)f2bf(a) | ((u32)f2bf(b) << 16);
}
__device__ __forceinline__ void gload_lds16(const void* g, void* l) {
  __builtin_amdgcn_global_load_lds(
      (const __attribute__((address_space(1))) u32*)g,
      (__attribute__((address_space(3))) u32*)l, 16, 0, 0);
}

// ---- kernel 1: W f32 -> bf16, LDS-image layout with baked XOR swizzle ------
// image granule (16B) within chunk: g = p*8 + (q ^ (p&7)),  q = kk/8
__global__ void prep_w(const float* __restrict__ W, u16* __restrict__ Wt) {
  int u  = blockIdx.x * 256 + threadIdx.x;   // exactly NCH*PCOL*8 units
  int q  = u & 7;
  int p  = (u >> 3) % PCOL;
  int ch = u / (PCOL * 8);
  int j = p & 63, co = p >> 6;
  const float* src = W + (size_t)(j * 3 + co) * 16576 + ch * 64 + q * 8;
  float4 fa = *(const float4*)src;
  float4 fb = *(const float4*)(src + 4);
  uint4 v;
  v.x = pk2(fa.x, fa.y); v.y = pk2(fa.z, fa.w);
  v.z = pk2(fb.x, fb.y); v.w = pk2(fb.z, fb.w);
  ((uint4*)Wt)[(size_t)ch * 1536 + p * 8 + (q ^ (p & 7))] = v;
}

// ---- kernel 2: bf16 MFMA GEMM. A: depth-2 reg prefetch (T14). B: depth-2
// LDS DMA via two-barrier loop — barrier2 (lgkm-only, cheap) retires the
// just-read B buffer so B(ch+2) DMA gets ~1.7 iterations of latency cover.
// No explicit vmcnt in the loop: CONV's compiler-inserted wait for A(ch+1)
// regs drains the older B(ch+1) DMA in the in-order vmcnt queue.
__global__ __launch_bounds__(256, 2)
void gemm_bf16(const float* __restrict__ x, const float* __restrict__ seeds,
               const u16* __restrict__ Wt, float* __restrict__ dst,
               const float* __restrict__ bias, int S) {
  __shared__ __align__(16) u16 lds[2][16384];   // per buf: A[0,4096) B[4096,16384)
  const int tid  = threadIdx.x;
  const int lane = tid & 63;
  const int wid  = tid >> 6;
  const int bid  = blockIdx.x;
  int mblk, ksp;
  if (S == 8) { ksp = bid & 7;  mblk = bid >> 3; }   // XCD-pinned split
  else        { mblk = bid & 63; ksp = bid >> 6; }
  const int n  = mblk >> 2;
  const int t0 = (mblk & 3) << 6;
  const int c0 = (NCH * ksp) / S;
  const int c1 = (NCH * (ksp + 1)) / S;

  const int q0 = tid & 7;          // A staging: 8-float unit within row
  const int m0 = tid >> 3;         // A staging: rows m0, m0+32
  const int lr = lane & 15, lq = lane >> 4;

  f32x4 acc[4][3] = {};

  struct ASet { float4 r0a, r0b, r1a, r1b; };
  ASet AX, AY;

  auto Bi = [&](int ch, int buf) {   // 6 x global_load_lds dwordx4 (24KB)
    const char* gsrc = (const char*)Wt + (size_t)ch * 24576 + wid * 1024 + lane * 16;
    char* lbase = (char*)&lds[buf][4096] + wid * 1024;
    #pragma unroll
    for (int r = 0; r < 6; ++r)
      gload_lds16(gsrc + (size_t)r * 4096, lbase + r * 4096);
  };
  auto Ai = [&](int ch, ASet& s) {   // 4 x global_load_dwordx4 into VGPRs
    const float *a0, *a1;
    if (ch < NCHX) {
      a0 = x + (((size_t)n * CIN + ch) * TDIM + (t0 + m0)) * VDIM + q0 * 8;
      a1 = a0 + (size_t)32 * VDIM;
    } else {
      a0 = seeds + ((size_t)n * TDIM + (t0 + m0)) * 192 + (ch - NCHX) * 64 + q0 * 8;
      a1 = a0 + (size_t)32 * 192;
    }
    s.r0a = *(const float4*)a0; s.r0b = *(const float4*)(a0 + 4);
    s.r1a = *(const float4*)a1; s.r1b = *(const float4*)(a1 + 4);
  };
  auto CONV = [&](const ASet& s, int buf) {  // bf16-pack + swizzled ds_write
    uint4 v;
    v.x = pk2(s.r0a.x, s.r0a.y); v.y = pk2(s.r0a.z, s.r0a.w);
    v.z = pk2(s.r0b.x, s.r0b.y); v.w = pk2(s.r0b.z, s.r0b.w);
    ((uint4*)&lds[buf][0])[m0 * 8 + (q0 ^ (m0 & 7))] = v;
    int m1 = m0 + 32;
    v.x = pk2(s.r1a.x, s.r1a.y); v.y = pk2(s.r1a.z, s.r1a.w);
    v.z = pk2(s.r1b.x, s.r1b.y); v.w = pk2(s.r1b.z, s.r1b.w);
    ((uint4*)&lds[buf][0])[m1 * 8 + (q0 ^ (m1 & 7))] = v;
  };

  auto COMPUTE = [&](int buf) {
    const u16* L = &lds[buf][0];
    #pragma unroll
    for (int ks = 0; ks < 2; ++ks) {
      const int q = ks * 4 + lq;
      bf16x8 af[4], bfr[3];
      #pragma unroll
      for (int mt = 0; mt < 4; ++mt) {
        int m = mt * 16 + lr;
        af[mt] = *(const bf16x8*)(L + (m * 8 + (q ^ (m & 7))) * 8);
      }
      #pragma unroll
      for (int nt = 0; nt < 3; ++nt) {
        int p = wid * 48 + nt * 16 + lr;
        bfr[nt] = *(const bf16x8*)(L + 4096 + (p * 8 + (q ^ (p & 7))) * 8);
      }
      #pragma unroll
      for (int mt = 0; mt < 4; ++mt)
        #pragma unroll
        for (int nt = 0; nt < 3; ++nt)
          acc[mt][nt] = __builtin_amdgcn_mfma_f32_16x16x32_bf16(
              af[mt], bfr[nt], acc[mt][nt], 0, 0, 0);
    }
  };

  // ---- prologue: B(c0)->buf0, B(c0+1)->buf1 (DMA); A(c0),A(c0+1)->regs ----
  Bi(c0, 0);
  Ai(c0, AX);
  if (c0 + 1 < c1) { Bi(c0 + 1, 1); Ai(c0 + 1, AY); }
  __builtin_amdgcn_sched_barrier(0);
  CONV(AX, 0);   // auto vmcnt wait for A(c0) regs => older B(c0) DMA drained too
  asm volatile("s_waitcnt lgkmcnt(0)" ::: "memory");
  __builtin_amdgcn_sched_barrier(0);
  __builtin_amdgcn_s_barrier();                 // barrier1
  __builtin_amdgcn_sched_barrier(0);

  // ---- main loop, unrolled x2 (named A-sets; rule #20) --------------------
  // iter ch (parity P=(ch-c0)&1): COMPUTE(P); barrier2; DMA B(ch+2)->P;
  // load A(ch+2)->AN; CONV A(ch+1)->P^1; barrier1.
#define PHASE(PAR, AP, AN)                                                    \
  {                                                                           \
    COMPUTE(PAR);                                                             \
    const bool hasN  = (ch + 1 < c1);                                         \
    const bool hasNN = (ch + 2 < c1);                                         \
    if (!hasN) break;                                                         \
    asm volatile("s_waitcnt lgkmcnt(0)" ::: "memory");                        \
    __builtin_amdgcn_sched_barrier(0);                                        \
    __builtin_amdgcn_s_barrier();               /* barrier2: B buf retired */ \
    __builtin_amdgcn_sched_barrier(0);                                        \
    if (hasNN) { Bi(ch + 2, PAR); Ai(ch + 2, AN); }                           \
    __builtin_amdgcn_sched_barrier(0);                                        \
    CONV(AP, (PAR) ^ 1);    /* auto-wait drains A(ch+1) & older B(ch+1) */    \
    asm volatile("s_waitcnt lgkmcnt(0)" ::: "memory");                        \
    __builtin_amdgcn_sched_barrier(0);                                        \
    __builtin_amdgcn_s_barrier();               /* barrier1 */                \
    __builtin_amdgcn_sched_barrier(0);                                        \
  }

  int ch = c0;
  while (true) {
    PHASE(0, AY, AX)     // compute ch (even parity)
    ++ch;
    PHASE(1, AX, AY)     // compute ch (odd parity)
    ++ch;
  }
#undef PHASE

  // epilogue: C layout col=lane&15, row=(lane>>4)*4+reg  [measured m89/m91]
  float* dbase = dst + (size_t)ksp * MTOT * PCOL;
  #pragma unroll
  for (int mt = 0; mt < 4; ++mt)
    #pragma unroll
    for (int nt = 0; nt < 3; ++nt) {
      int col = wid * 48 + nt * 16 + lr;
      float bv = bias ? bias[(col & 63) * 3 + (col >> 6)] : 0.f;
      #pragma unroll
      for (int r = 0; r < 4; ++r) {
        int row = mblk * 64 + mt * 16 + lq * 4 + r;
        dbase[(size_t)row * PCOL + col] = acc[mt][nt][r] + bv;
      }
    }
}

// ---- kernel 3: deterministic K-split reduction + bias ----------------------
__global__ void reduce_k(const float* __restrict__ part, const float* __restrict__ b,
                         float* __restrict__ out, int S) {
  int i4 = (blockIdx.x * 256 + threadIdx.x) * 4;   // exact: MTOT*PCOL/4 threads
  float4 a = *(const float4*)&part[i4];
  for (int s = 1; s < S; ++s) {
    const float4 v = *(const float4*)&part[(size_t)s * (MTOT * PCOL) + i4];
    a.x += v.x; a.y += v.y; a.z += v.z; a.w += v.w;
  }
  int p0 = i4 % PCOL;
  a.x += b[((p0 + 0) & 63) * 3 + ((p0 + 0) >> 6)];
  a.y += b[((p0 + 1) & 63) * 3 + ((p0 + 1) >> 6)];
  a.z += b[((p0 + 2) & 63) * 3 + ((p0 + 2) >> 6)];
  a.w += b[((p0 + 3) & 63) * 3 + ((p0 + 3) >> 6)];
  *(float4*)&out[i4] = a;
}

// ---- insurance fallback if ws too small for the Wt image (unlikely) --------
__global__ void fallback_k(const float* __restrict__ x, const float* __restrict__ seeds,
                           const float* __restrict__ W, const float* __restrict__ b,
                           float* __restrict__ out) {
  __shared__ float mk[512];
  int m = blockIdx.x, n = m >> 8, t = m & 255, p = threadIdx.x;
  float acc = 0.f;
  for (int k0 = 0; k0 < 16576; k0 += 512) {
    int kn = min(512, 16576 - k0);
    __syncthreads();
    for (int i = threadIdx.x; i < kn; i += 256) {
      int k = k0 + i;
      mk[i] = (k < 16384)
                ? x[(((size_t)n * 256 + (k >> 6)) * 256 + t) * 64 + (k & 63)]
                : seeds[((size_t)n * 256 + t) * 192 + (k - 16384)];
    }
    __syncthreads();
    if (p < PCOL) {
      const float* wr = W + (size_t)((p & 63) * 3 + (p >> 6)) * 16576 + k0;
      for (int i = 0; i < kn; ++i) acc += mk[i] * wr[i];
    }
  }
  if (p < PCOL) out[(size_t)m * PCOL + p] = acc + b[(p & 63) * 3 + (p >> 6)];
}

extern "C" void kernel_launch(void* const* d_in, const int* in_sizes, int n_in,
                              void* d_out, int out_size, void* d_ws, size_t ws_size,
                              hipStream_t stream) {
  (void)in_sizes; (void)n_in; (void)out_size;
  const float* x     = (const float*)d_in[0];
  const float* seeds = (const float*)d_in[1];
  const float* W     = (const float*)d_in[2];
  const float* b     = (const float*)d_in[3];
  float* out = (float*)d_out;

  if (ws_size < WT_BYTES) {              // no room for bf16 weight image
    fallback_k<<<dim3(MTOT), dim3(256), 0, stream>>>(x, seeds, W, b, out);
    return;
  }
  u16* Wt = (u16*)d_ws;
  int S = 8;                             // K-split for grid = 64*S blocks
  while (S > 1 && WT_BYTES + (size_t)S * MTOT * PCOL * 4 > ws_size) S >>= 1;
  if (WT_BYTES + (size_t)S * MTOT * PCOL * 4 > ws_size) S = 1;

  prep_w<<<dim3((NCH * PCOL * 8) / 256), dim3(256), 0, stream>>>(W, Wt);
  if (S == 1) {
    gemm_bf16<<<dim3(64), dim3(256), 0, stream>>>(x, seeds, Wt, out, b, 1);
  } else {
    float* part = (float*)((char*)d_ws + WT_BYTES);
    gemm_bf16<<<dim3(64 * S), dim3(256), 0, stream>>>(x, seeds, Wt, part, nullptr, S);
    reduce_k<<<dim3(MTOT * PCOL / 4 / 256), dim3(256), 0, stream>>>(part, b, out, S);
  }
}